// Round 1
// baseline (2724.596 us; speedup 1.0000x reference)
//
#include <hip/hip_runtime.h>
#include <math.h>

// Problem constants
#define BB 2
#define SS 2048
#define EE 768
#define HH 12
#define DD 64
#define FF 3072
#define BSROWS (BB*SS)      // 4096
#define HD (HH*DD)          // 768

// ---------------------------------------------------------------------------
// LayerNorm: one block (256 thr) per row of 768
// ---------------------------------------------------------------------------
__global__ __launch_bounds__(256)
void ln_kernel(const float* __restrict__ x, const float* __restrict__ g,
               const float* __restrict__ bt, float* __restrict__ o)
{
    const int row = blockIdx.x;
    const float* xr = x + (size_t)row * EE;
    const int t = threadIdx.x;
    float v0 = xr[t], v1 = xr[t + 256], v2 = xr[t + 512];
    float s = v0 + v1 + v2;
    #pragma unroll
    for (int off = 32; off > 0; off >>= 1) s += __shfl_xor(s, off);
    __shared__ float red[8];
    const int w = t >> 6;
    if ((t & 63) == 0) red[w] = s;
    __syncthreads();
    const float mean = (red[0] + red[1] + red[2] + red[3]) * (1.f / 768.f);
    float d0 = v0 - mean, d1 = v1 - mean, d2 = v2 - mean;
    float q = d0 * d0 + d1 * d1 + d2 * d2;
    #pragma unroll
    for (int off = 32; off > 0; off >>= 1) q += __shfl_xor(q, off);
    if ((t & 63) == 0) red[4 + w] = q;
    __syncthreads();
    const float var = (red[4] + red[5] + red[6] + red[7]) * (1.f / 768.f);
    const float rstd = rsqrtf(var + 1e-5f);
    float* orow = o + (size_t)row * EE;
    orow[t]       = d0 * rstd * g[t]       + bt[t];
    orow[t + 256] = d1 * rstd * g[t + 256] + bt[t + 256];
    orow[t + 512] = d2 * rstd * g[t + 512] + bt[t + 512];
}

// ---------------------------------------------------------------------------
// Repack Wq/Wv: [H,E,D] -> [E, H*D]
// ---------------------------------------------------------------------------
__global__ __launch_bounds__(256)
void repack_kernel(const float* __restrict__ w, float* __restrict__ o)
{
    int i = blockIdx.x * 256 + threadIdx.x;        // over E*HD = 589824
    int e = i / HD;
    int rem = i - e * HD;
    int h = rem >> 6;
    int d = rem & 63;
    o[i] = w[((size_t)h * EE + e) * DD + d];
}

// ---------------------------------------------------------------------------
// SIMT f32 GEMM: C[M,N] = A[M,K] @ B[K,N] + bias (+res) (relu?)
// BN=128 fixed, BM template {64,128}, BK=16, 256 threads.
// Thread (tx=t&15, ty=t>>4) computes rows ty*R..+R, cols {tx*4..+4, 64+tx*4..+4}
// ---------------------------------------------------------------------------
template<int BM, bool RELU, bool HAS_RES>
__global__ __launch_bounds__(256)
void gemm_kernel(const float* __restrict__ A, const float* __restrict__ B,
                 const float* __restrict__ bias, const float* res,
                 float* C, int M, int N, int K)
{
    constexpr int BN = 128, BK = 16;
    constexpr int R = BM / 16;
    __shared__ float As[BK][BM];
    __shared__ float Bs[BK][BN];
    const int t = threadIdx.x;
    const int tx = t & 15, ty = t >> 4;
    const int m0 = blockIdx.y * BM, n0 = blockIdx.x * BN;
    float acc[R][8];
    #pragma unroll
    for (int i = 0; i < R; ++i)
        #pragma unroll
        for (int j = 0; j < 8; ++j) acc[i][j] = 0.f;

    const int bk = t >> 4;     // B-tile k row
    const int bj = t & 15;     // B-tile float4 group

    for (int k0 = 0; k0 < K; k0 += BK) {
        __syncthreads();
        #pragma unroll
        for (int idx = 0; idx < BM / 64; ++idx) {
            int f = t + idx * 256;
            int row = f >> 2, kc = f & 3;
            float4 v = *(const float4*)&A[(size_t)(m0 + row) * K + k0 + kc * 4];
            As[kc * 4 + 0][row] = v.x;
            As[kc * 4 + 1][row] = v.y;
            As[kc * 4 + 2][row] = v.z;
            As[kc * 4 + 3][row] = v.w;
        }
        {
            const float* bp = &B[(size_t)(k0 + bk) * N + n0 + bj * 4];
            float4 v0 = *(const float4*)bp;
            float4 v1 = *(const float4*)(bp + 64);
            *(float4*)&Bs[bk][bj * 4]      = v0;
            *(float4*)&Bs[bk][bj * 4 + 64] = v1;
        }
        __syncthreads();
        #pragma unroll
        for (int kk = 0; kk < BK; ++kk) {
            float a[R], b[8];
            #pragma unroll
            for (int i = 0; i < R; i += 4)
                *(float4*)&a[i] = *(const float4*)&As[kk][ty * R + i];
            *(float4*)&b[0] = *(const float4*)&Bs[kk][tx * 4];
            *(float4*)&b[4] = *(const float4*)&Bs[kk][64 + tx * 4];
            #pragma unroll
            for (int i = 0; i < R; ++i)
                #pragma unroll
                for (int j = 0; j < 8; ++j)
                    acc[i][j] += a[i] * b[j];
        }
    }
    // epilogue
    float bn[8];
    *(float4*)&bn[0] = *(const float4*)&bias[n0 + tx * 4];
    *(float4*)&bn[4] = *(const float4*)&bias[n0 + 64 + tx * 4];
    #pragma unroll
    for (int i = 0; i < R; ++i) {
        const size_t m = m0 + ty * R + i;
        float out0[4], out1[4];
        #pragma unroll
        for (int j = 0; j < 4; ++j) {
            out0[j] = acc[i][j]     + bn[j];
            out1[j] = acc[i][j + 4] + bn[j + 4];
        }
        if (HAS_RES) {
            float4 r0 = *(const float4*)&res[m * N + n0 + tx * 4];
            float4 r1 = *(const float4*)&res[m * N + n0 + 64 + tx * 4];
            out0[0] += r0.x; out0[1] += r0.y; out0[2] += r0.z; out0[3] += r0.w;
            out1[0] += r1.x; out1[1] += r1.y; out1[2] += r1.z; out1[3] += r1.w;
        }
        if (RELU) {
            #pragma unroll
            for (int j = 0; j < 4; ++j) {
                out0[j] = fmaxf(out0[j], 0.f);
                out1[j] = fmaxf(out1[j], 0.f);
            }
        }
        *(float4*)&C[m * N + n0 + tx * 4]      = *(float4*)&out0[0];
        *(float4*)&C[m * N + n0 + 64 + tx * 4] = *(float4*)&out1[0];
    }
}

// ---------------------------------------------------------------------------
// Flash-style attention. q layout [B,S,H*D] (col = h*64+d), k = q (source bug),
// v same layout. Causal + input_mask columns; all-masked row -> out = v[row].
// Block: 256 thr, 64 query rows (r=t>>2), 4 col/d quarters (q4=t&3).
// ---------------------------------------------------------------------------
__global__ __launch_bounds__(256)
void attn_kernel(const float* __restrict__ qg, const float* __restrict__ vg,
                 const int* __restrict__ maskg, float* __restrict__ outg)
{
    const int qt = blockIdx.x;   // 0..31
    const int h  = blockIdx.y;   // 0..11
    const int b  = blockIdx.z;   // 0..1
    __shared__ float qs[64][68];
    __shared__ float ks[64][68];
    __shared__ float vs[64][68];
    __shared__ float sc[64][68];
    __shared__ int   msk[64];
    const int t  = threadIdx.x;
    const int r  = t >> 2;
    const int q4 = t & 3;
    const int sg = qt * 64 + r;       // global query row
    const int d0 = q4 * 16;

    {   // load Q tile, pre-scaled by 1/sqrt(D)=0.125
        const float* src = qg + ((size_t)(b * SS + sg) * HD + h * 64 + d0);
        #pragma unroll
        for (int i = 0; i < 4; ++i) {
            float4 v = *(const float4*)(src + 4 * i);
            v.x *= 0.125f; v.y *= 0.125f; v.z *= 0.125f; v.w *= 0.125f;
            *(float4*)&qs[r][d0 + 4 * i] = v;
        }
    }
    float o[16];
    #pragma unroll
    for (int i = 0; i < 16; ++i) o[i] = 0.f;
    float run_m = -INFINITY, run_l = 0.f;

    for (int kvt = 0; kvt <= qt; ++kvt) {
        __syncthreads();   // protect ks/vs/sc from previous iteration's readers
        {
            const size_t base = (size_t)(b * SS + kvt * 64 + r) * HD + h * 64 + d0;
            const float* ksrc = qg + base;   // k = q
            const float* vsrc = vg + base;
            #pragma unroll
            for (int i = 0; i < 4; ++i) {
                *(float4*)&ks[r][d0 + 4 * i] = *(const float4*)(ksrc + 4 * i);
                *(float4*)&vs[r][d0 + 4 * i] = *(const float4*)(vsrc + 4 * i);
            }
            if (t < 64) msk[t] = maskg[b * SS + kvt * 64 + t];
        }
        __syncthreads();
        // scores for cols d0..d0+15
        float s[16];
        #pragma unroll
        for (int cc = 0; cc < 16; ++cc) s[cc] = 0.f;
        #pragma unroll 4
        for (int dd = 0; dd < 64; dd += 4) {
            float4 qv = *(const float4*)&qs[r][dd];
            #pragma unroll
            for (int cc = 0; cc < 16; ++cc) {
                float4 kv = *(const float4*)&ks[d0 + cc][dd];
                s[cc] += qv.x * kv.x + qv.y * kv.y + qv.z * kv.z + qv.w * kv.w;
            }
        }
        float lm = -INFINITY;
        #pragma unroll
        for (int cc = 0; cc < 16; ++cc) {
            int cg = kvt * 64 + d0 + cc;
            bool valid = (cg <= sg) && (msk[d0 + cc] != 0);
            s[cc] = valid ? s[cc] : -INFINITY;
            lm = fmaxf(lm, s[cc]);
        }
        lm = fmaxf(lm, __shfl_xor(lm, 1));
        lm = fmaxf(lm, __shfl_xor(lm, 2));
        const float newm = fmaxf(run_m, lm);
        float alpha, tsum = 0.f;
        if (newm == -INFINITY) {           // nothing valid so far at all
            alpha = 1.f;
            #pragma unroll
            for (int cc = 0; cc < 16; ++cc) s[cc] = 0.f;
        } else {
            alpha = __expf(run_m - newm);  // run_m=-inf -> 0, fine
            #pragma unroll
            for (int cc = 0; cc < 16; ++cc) {
                s[cc] = (s[cc] == -INFINITY) ? 0.f : __expf(s[cc] - newm);
                tsum += s[cc];
            }
        }
        tsum += __shfl_xor(tsum, 1);
        tsum += __shfl_xor(tsum, 2);
        run_l = run_l * alpha + tsum;
        run_m = newm;
        #pragma unroll
        for (int cc = 0; cc < 16; ++cc) sc[r][d0 + cc] = s[cc];
        __syncthreads();
        #pragma unroll
        for (int i = 0; i < 16; ++i) o[i] *= alpha;
        #pragma unroll 4
        for (int c = 0; c < 64; ++c) {
            float p = sc[r][c];
            const float* vrow = &vs[c][d0];
            #pragma unroll
            for (int i = 0; i < 4; ++i) {
                float4 vv = *(const float4*)(vrow + 4 * i);
                o[4 * i + 0] += p * vv.x;
                o[4 * i + 1] += p * vv.y;
                o[4 * i + 2] += p * vv.z;
                o[4 * i + 3] += p * vv.w;
            }
        }
    }
    float* dst = outg + ((size_t)(b * SS + sg) * HD + h * 64 + d0);
    if (run_l > 0.f) {
        const float inv = 1.f / run_l;
        #pragma unroll
        for (int i = 0; i < 4; ++i) {
            float4 v;
            v.x = o[4 * i + 0] * inv; v.y = o[4 * i + 1] * inv;
            v.z = o[4 * i + 2] * inv; v.w = o[4 * i + 3] * inv;
            *(float4*)(dst + 4 * i) = v;
        }
    } else {  // row fully masked -> reference puts 1.0 on diagonal -> out = v[row]
        const float* vsrc = vg + ((size_t)(b * SS + sg) * HD + h * 64 + d0);
        #pragma unroll
        for (int i = 0; i < 4; ++i)
            *(float4*)(dst + 4 * i) = *(const float4*)(vsrc + 4 * i);
    }
}

// ---------------------------------------------------------------------------
extern "C" void kernel_launch(void* const* d_in, const int* in_sizes, int n_in,
                              void* d_out, int out_size, void* d_ws, size_t ws_size,
                              hipStream_t stream)
{
    const float* x    = (const float*)d_in[0];
    const float* Wq   = (const float*)d_in[1];
    const float* bq   = (const float*)d_in[2];
    const float* Wv   = (const float*)d_in[3];
    const float* bv   = (const float*)d_in[4];
    const float* Wo   = (const float*)d_in[5];
    const float* bo   = (const float*)d_in[6];
    const float* ln1g = (const float*)d_in[7];
    const float* ln1b = (const float*)d_in[8];
    const float* W1   = (const float*)d_in[9];
    const float* b1   = (const float*)d_in[10];
    const float* W2   = (const float*)d_in[11];
    const float* b2   = (const float*)d_in[12];
    const float* W3   = (const float*)d_in[13];
    const float* b3   = (const float*)d_in[14];
    const float* ln2g = (const float*)d_in[15];
    const float* ln2b = (const float*)d_in[16];
    const int*   mask = (const int*)d_in[17];
    float* out = (float*)d_out;
    float* ws  = (float*)d_ws;

    // workspace layout (floats): needs (2*BS*F + 2*E*HD)*4 = ~105.4 MB
    const size_t RSZ = (size_t)BSROWS * FF;        // 12,582,912 floats
    float* region0 = ws;
    float* region1 = ws + RSZ;
    float* wqp = ws + 2 * RSZ;                     // [E, HD]
    float* wvp = wqp + (size_t)EE * HD;

    float* xln   = region0;
    float* qb    = region0 + (size_t)BSROWS * EE;
    float* vb    = region0 + 2 * (size_t)BSROWS * EE;
    float* attno = region0 + 3 * (size_t)BSROWS * EE;

    // 1. repack Wq, Wv
    repack_kernel<<<(EE * HD) / 256, 256, 0, stream>>>(Wq, wqp);
    repack_kernel<<<(EE * HD) / 256, 256, 0, stream>>>(Wv, wvp);
    // 2. LN1
    ln_kernel<<<BSROWS, 256, 0, stream>>>(x, ln1g, ln1b, xln);
    // 3. q/v projections: [4096,768] = xln @ [768,768] + bias
    dim3 gp(HD / 128, BSROWS / 64);
    gemm_kernel<64, false, false><<<gp, 256, 0, stream>>>(xln, wqp, bq, nullptr, qb, BSROWS, HD, EE);
    gemm_kernel<64, false, false><<<gp, 256, 0, stream>>>(xln, wvp, bv, nullptr, vb, BSROWS, HD, EE);
    // 4. attention
    attn_kernel<<<dim3(SS / 64, HH, BB), 256, 0, stream>>>(qb, vb, mask, attno);
    // 5. output projection + residual x -> out (= y1)
    gemm_kernel<64, false, true><<<gp, 256, 0, stream>>>(attno, Wo, bo, x, out, BSROWS, EE, HD);
    // 6. LN2: out -> region1 (y1ln)
    float* y1ln = region1;
    ln_kernel<<<BSROWS, 256, 0, stream>>>(out, ln2g, ln2b, y1ln);
    // 7. FF1: h1 = relu(y1ln @ W1 + b1) -> region0 (overwrites dead xln/q/v/attno)
    dim3 gf(FF / 128, BSROWS / 128);
    gemm_kernel<128, true, false><<<gf, 256, 0, stream>>>(y1ln, W1, b1, nullptr, region0, BSROWS, FF, EE);
    // 8. FF2: h2 = relu(h1 @ W2 + b2) -> region1 (overwrites dead y1ln)
    gemm_kernel<128, true, false><<<gf, 256, 0, stream>>>(region0, W2, b2, nullptr, region1, BSROWS, FF, FF);
    // 9. FF3: out = h2 @ W3 + b3 + y1(out)
    dim3 g3(EE / 128, BSROWS / 64);
    gemm_kernel<64, false, true><<<g3, 256, 0, stream>>>(region1, W3, b3, out, out, BSROWS, EE, FF);
}

// Round 3
// 1299.199 us; speedup vs baseline: 2.0971x; 2.0971x over previous
//
#include <hip/hip_runtime.h>
#include <hip/hip_bf16.h>
#include <math.h>

// Problem constants
#define BB 2
#define SS 2048
#define EE 768
#define HH 12
#define DD 64
#define FF 3072
#define BSROWS (BB*SS)      // 4096
#define HD (HH*DD)          // 768

typedef __hip_bfloat16 bf16;
typedef __attribute__((ext_vector_type(8))) short short8;
typedef __attribute__((ext_vector_type(4))) float f32x4;

__device__ inline void store_val(float* p, float v) { *p = v; }
__device__ inline void store_val(bf16* p, float v)  { *p = __float2bfloat16(v); }

// ---------------------------------------------------------------------------
// Tiled transpose + f32->bf16 convert: in [R,C] f32 (z-slice) -> out [C,R] bf16
// ---------------------------------------------------------------------------
__global__ __launch_bounds__(256)
void transpose_bf16(const float* __restrict__ in, bf16* __restrict__ out,
                    int R, int C)
{
    __shared__ float tile[32][33];
    const int t = threadIdx.x;
    const size_t zoff = (size_t)blockIdx.z * R * C;
    const int r0 = blockIdx.y * 32, c0 = blockIdx.x * 32;
    const int lr = t >> 5, lc = t & 31;
    #pragma unroll
    for (int i = 0; i < 4; ++i)
        tile[lr + 8 * i][lc] = in[zoff + (size_t)(r0 + lr + 8 * i) * C + c0 + lc];
    __syncthreads();
    #pragma unroll
    for (int i = 0; i < 4; ++i)
        out[zoff + (size_t)(c0 + lr + 8 * i) * R + r0 + lc] =
            __float2bfloat16(tile[lc][lr + 8 * i]);
}

// ---------------------------------------------------------------------------
// LayerNorm: one block (256 thr) per row of 768; f32 in, OutT out
// ---------------------------------------------------------------------------
template<typename OutT>
__global__ __launch_bounds__(256)
void ln_kernel(const float* __restrict__ x, const float* __restrict__ g,
               const float* __restrict__ bt, OutT* __restrict__ o)
{
    const int row = blockIdx.x;
    const float* xr = x + (size_t)row * EE;
    const int t = threadIdx.x;
    float v0 = xr[t], v1 = xr[t + 256], v2 = xr[t + 512];
    float s = v0 + v1 + v2;
    #pragma unroll
    for (int off = 32; off > 0; off >>= 1) s += __shfl_xor(s, off);
    __shared__ float red[8];
    const int w = t >> 6;
    if ((t & 63) == 0) red[w] = s;
    __syncthreads();
    const float mean = (red[0] + red[1] + red[2] + red[3]) * (1.f / 768.f);
    float d0 = v0 - mean, d1 = v1 - mean, d2 = v2 - mean;
    float q = d0 * d0 + d1 * d1 + d2 * d2;
    #pragma unroll
    for (int off = 32; off > 0; off >>= 1) q += __shfl_xor(q, off);
    if ((t & 63) == 0) red[4 + w] = q;
    __syncthreads();
    const float var = (red[4] + red[5] + red[6] + red[7]) * (1.f / 768.f);
    const float rstd = rsqrtf(var + 1e-5f);
    OutT* orow = o + (size_t)row * EE;
    store_val(&orow[t],       d0 * rstd * g[t]       + bt[t]);
    store_val(&orow[t + 256], d1 * rstd * g[t + 256] + bt[t + 256]);
    store_val(&orow[t + 512], d2 * rstd * g[t + 512] + bt[t + 512]);
}

// ---------------------------------------------------------------------------
// bf16 MFMA GEMM: C[M,N] = A[M,K](bf16) @ Bt[N,K](bf16)^T + bias (+res)(relu?)
// 128x128 tile, BK=64, 4 waves (2x2), wave tile 64x64 (4x4 frags of 16x16x32).
// LDS chunk slot = c ^ (row&7): XOR swizzle applied on the pre-swizzled GLOBAL
// source (LDS dest linear, per m104/m108/rule-21); read applies the same XOR.
// res and C must NOT alias (C is written exactly once, never read).
// ---------------------------------------------------------------------------
template<typename OutT, bool RELU, bool HAS_RES>
__global__ __launch_bounds__(256, 2)
void mfma_gemm(const bf16* __restrict__ A, const bf16* __restrict__ Bt,
               const float* __restrict__ bias, const float* __restrict__ res,
               OutT* __restrict__ C, int M, int N, int K)
{
    __shared__ bf16 As[128 * 64];
    __shared__ bf16 Bs[128 * 64];
    const int t = threadIdx.x;
    const int lane = t & 63;
    const int w = t >> 6;
    const int wm = w >> 1, wn = w & 1;
    const int m0 = blockIdx.y * 128, n0 = blockIdx.x * 128;
    const int fr = lane & 15;   // fragment row/col within 16
    const int fq = lane >> 4;   // k-quarter / reg group

    f32x4 acc[4][4];
    #pragma unroll
    for (int i = 0; i < 4; ++i)
        #pragma unroll
        for (int j = 0; j < 4; ++j)
            acc[i][j] = (f32x4){0.f, 0.f, 0.f, 0.f};

    for (int k0 = 0; k0 < K; k0 += 64) {
        // drain prior LDS reads before overwriting the tiles
        asm volatile("s_waitcnt lgkmcnt(0)" ::: "memory");
        __syncthreads();
        #pragma unroll
        for (int i = 0; i < 4; ++i) {
            const int p = (w * 4 + i) * 64 + lane;  // physical 16B chunk
            const int m = p >> 3;                   // tile row
            const int c = (p & 7) ^ (m & 7);        // logical k-chunk
            const bf16* ga = &A [(size_t)(m0 + m) * K + k0 + c * 8];
            const bf16* gb = &Bt[(size_t)(n0 + m) * K + k0 + c * 8];
            bf16* la = &As[(size_t)(w * 4 + i) * 512];
            bf16* lb = &Bs[(size_t)(w * 4 + i) * 512];
            __builtin_amdgcn_global_load_lds(
                (const __attribute__((address_space(1))) unsigned int*)ga,
                (__attribute__((address_space(3))) unsigned int*)la, 16, 0, 0);
            __builtin_amdgcn_global_load_lds(
                (const __attribute__((address_space(1))) unsigned int*)gb,
                (__attribute__((address_space(3))) unsigned int*)lb, 16, 0, 0);
        }
        // drain the DMA writes before any wave crosses the barrier
        asm volatile("s_waitcnt vmcnt(0)" ::: "memory");
        __syncthreads();

        short8 af[4][2], bfr[4][2];
        #pragma unroll
        for (int mi = 0; mi < 4; ++mi) {
            const int row = wm * 64 + mi * 16 + fr;
            #pragma unroll
            for (int kh = 0; kh < 2; ++kh) {
                const int slot = (kh * 4 + fq) ^ (row & 7);
                af[mi][kh] = *(const short8*)&As[row * 64 + slot * 8];
            }
        }
        #pragma unroll
        for (int ni = 0; ni < 4; ++ni) {
            const int row = wn * 64 + ni * 16 + fr;
            #pragma unroll
            for (int kh = 0; kh < 2; ++kh) {
                const int slot = (kh * 4 + fq) ^ (row & 7);
                bfr[ni][kh] = *(const short8*)&Bs[row * 64 + slot * 8];
            }
        }
        #pragma unroll
        for (int mi = 0; mi < 4; ++mi)
            #pragma unroll
            for (int ni = 0; ni < 4; ++ni) {
                acc[mi][ni] = __builtin_amdgcn_mfma_f32_16x16x32_bf16(
                    af[mi][0], bfr[ni][0], acc[mi][ni], 0, 0, 0);
                acc[mi][ni] = __builtin_amdgcn_mfma_f32_16x16x32_bf16(
                    af[mi][1], bfr[ni][1], acc[mi][ni], 0, 0, 0);
            }
    }

    // epilogue: C/D layout col=lane&15, row=(lane>>4)*4+reg  [m89/m91]
    #pragma unroll
    for (int ni = 0; ni < 4; ++ni) {
        const int cn = n0 + wn * 64 + ni * 16 + fr;
        const float bv = bias[cn];
        #pragma unroll
        for (int mi = 0; mi < 4; ++mi) {
            const int rbase = m0 + wm * 64 + mi * 16 + fq * 4;
            #pragma unroll
            for (int j = 0; j < 4; ++j) {
                float v = acc[mi][ni][j] + bv;
                if (HAS_RES) v += res[(size_t)(rbase + j) * N + cn];
                if (RELU) v = fmaxf(v, 0.f);
                store_val(&C[(size_t)(rbase + j) * N + cn], v);
            }
        }
    }
}

// ---------------------------------------------------------------------------
// Flash-style attention (f32 math, bf16 out). q layout [B,S,H*D], k = q
// (source bug), v same. Causal + input_mask; all-masked row -> out = v[row].
// ---------------------------------------------------------------------------
__global__ __launch_bounds__(256)
void attn_kernel(const float* __restrict__ qg, const float* __restrict__ vg,
                 const int* __restrict__ maskg, bf16* __restrict__ outg)
{
    const int qt = blockIdx.x;
    const int h  = blockIdx.y;
    const int b  = blockIdx.z;
    __shared__ float qs[64][68];
    __shared__ float ks[64][68];
    __shared__ float vs[64][68];
    __shared__ float sc[64][68];
    __shared__ int   msk[64];
    const int t  = threadIdx.x;
    const int r  = t >> 2;
    const int q4 = t & 3;
    const int sg = qt * 64 + r;
    const int d0 = q4 * 16;

    {
        const float* src = qg + ((size_t)(b * SS + sg) * HD + h * 64 + d0);
        #pragma unroll
        for (int i = 0; i < 4; ++i) {
            float4 v = *(const float4*)(src + 4 * i);
            v.x *= 0.125f; v.y *= 0.125f; v.z *= 0.125f; v.w *= 0.125f;
            *(float4*)&qs[r][d0 + 4 * i] = v;
        }
    }
    float o[16];
    #pragma unroll
    for (int i = 0; i < 16; ++i) o[i] = 0.f;
    float run_m = -INFINITY, run_l = 0.f;

    for (int kvt = 0; kvt <= qt; ++kvt) {
        __syncthreads();
        {
            const size_t base = (size_t)(b * SS + kvt * 64 + r) * HD + h * 64 + d0;
            const float* ksrc = qg + base;   // k = q
            const float* vsrc = vg + base;
            #pragma unroll
            for (int i = 0; i < 4; ++i) {
                *(float4*)&ks[r][d0 + 4 * i] = *(const float4*)(ksrc + 4 * i);
                *(float4*)&vs[r][d0 + 4 * i] = *(const float4*)(vsrc + 4 * i);
            }
            if (t < 64) msk[t] = maskg[b * SS + kvt * 64 + t];
        }
        __syncthreads();
        float s[16];
        #pragma unroll
        for (int cc = 0; cc < 16; ++cc) s[cc] = 0.f;
        #pragma unroll 4
        for (int dd = 0; dd < 64; dd += 4) {
            float4 qv = *(const float4*)&qs[r][dd];
            #pragma unroll
            for (int cc = 0; cc < 16; ++cc) {
                float4 kv = *(const float4*)&ks[d0 + cc][dd];
                s[cc] += qv.x * kv.x + qv.y * kv.y + qv.z * kv.z + qv.w * kv.w;
            }
        }
        float lm = -INFINITY;
        #pragma unroll
        for (int cc = 0; cc < 16; ++cc) {
            int cg = kvt * 64 + d0 + cc;
            bool valid = (cg <= sg) && (msk[d0 + cc] != 0);
            s[cc] = valid ? s[cc] : -INFINITY;
            lm = fmaxf(lm, s[cc]);
        }
        lm = fmaxf(lm, __shfl_xor(lm, 1));
        lm = fmaxf(lm, __shfl_xor(lm, 2));
        const float newm = fmaxf(run_m, lm);
        float alpha, tsum = 0.f;
        if (newm == -INFINITY) {
            alpha = 1.f;
            #pragma unroll
            for (int cc = 0; cc < 16; ++cc) s[cc] = 0.f;
        } else {
            alpha = __expf(run_m - newm);
            #pragma unroll
            for (int cc = 0; cc < 16; ++cc) {
                s[cc] = (s[cc] == -INFINITY) ? 0.f : __expf(s[cc] - newm);
                tsum += s[cc];
            }
        }
        tsum += __shfl_xor(tsum, 1);
        tsum += __shfl_xor(tsum, 2);
        run_l = run_l * alpha + tsum;
        run_m = newm;
        #pragma unroll
        for (int cc = 0; cc < 16; ++cc) sc[r][d0 + cc] = s[cc];
        __syncthreads();
        #pragma unroll
        for (int i = 0; i < 16; ++i) o[i] *= alpha;
        #pragma unroll 4
        for (int c = 0; c < 64; ++c) {
            float p = sc[r][c];
            const float* vrow = &vs[c][d0];
            #pragma unroll
            for (int i = 0; i < 4; ++i) {
                float4 vv = *(const float4*)(vrow + 4 * i);
                o[4 * i + 0] += p * vv.x;
                o[4 * i + 1] += p * vv.y;
                o[4 * i + 2] += p * vv.z;
                o[4 * i + 3] += p * vv.w;
            }
        }
    }
    bf16* dst = outg + ((size_t)(b * SS + sg) * HD + h * 64 + d0);
    if (run_l > 0.f) {
        const float inv = 1.f / run_l;
        #pragma unroll
        for (int i = 0; i < 16; ++i)
            dst[i] = __float2bfloat16(o[i] * inv);
    } else {
        const float* vsrc = vg + ((size_t)(b * SS + sg) * HD + h * 64 + d0);
        #pragma unroll
        for (int i = 0; i < 16; ++i)
            dst[i] = __float2bfloat16(vsrc[i]);
    }
}

// ---------------------------------------------------------------------------
extern "C" void kernel_launch(void* const* d_in, const int* in_sizes, int n_in,
                              void* d_out, int out_size, void* d_ws, size_t ws_size,
                              hipStream_t stream)
{
    const float* x    = (const float*)d_in[0];
    const float* Wq   = (const float*)d_in[1];
    const float* bq   = (const float*)d_in[2];
    const float* Wv   = (const float*)d_in[3];
    const float* bv   = (const float*)d_in[4];
    const float* Wo   = (const float*)d_in[5];
    const float* bo   = (const float*)d_in[6];
    const float* ln1g = (const float*)d_in[7];
    const float* ln1b = (const float*)d_in[8];
    const float* W1   = (const float*)d_in[9];
    const float* b1   = (const float*)d_in[10];
    const float* W2   = (const float*)d_in[11];
    const float* b2   = (const float*)d_in[12];
    const float* W3   = (const float*)d_in[13];
    const float* b3   = (const float*)d_in[14];
    const float* ln2g = (const float*)d_in[15];
    const float* ln2b = (const float*)d_in[16];
    const int*   mask = (const int*)d_in[17];
    float* out = (float*)d_out;
    char* wsb  = (char*)d_ws;

    // workspace layout (bytes), total ~96.4 MB. Liveness-based aliasing:
    //   h1 over [qb|vb] (qb/vb dead after attn);  y1ln over xln (xln dead
    //   after q/v proj);  attno over h2[0:6.3MB] (attno dead before FF2).
    size_t off = 0;
    bf16* WqT = (bf16*)(wsb + off); off += (size_t)EE * HD * 2;   // [HD,E]
    bf16* WvT = (bf16*)(wsb + off); off += (size_t)EE * HD * 2;   // [HD,E]
    bf16* WoT = (bf16*)(wsb + off); off += (size_t)HD * EE * 2;   // [E,HD]
    bf16* W1T = (bf16*)(wsb + off); off += (size_t)EE * FF * 2;   // [F,E]
    bf16* W3T = (bf16*)(wsb + off); off += (size_t)FF * EE * 2;   // [E,F]
    bf16* W2T = (bf16*)(wsb + off); off += (size_t)FF * FF * 2;   // [F,F]
    float* qb = (float*)(wsb + off);                              // [BS,HD] f32
    bf16*  h1 = (bf16*)(wsb + off); off += (size_t)BSROWS * HD * 4;
    float* vb = (float*)(wsb + off); off += (size_t)BSROWS * HD * 4;
    bf16* xln = (bf16*)(wsb + off); off += (size_t)BSROWS * EE * 2;  // also y1ln
    bf16* h2  = (bf16*)(wsb + off);
    bf16* attno = h2;               off += (size_t)BSROWS * FF * 2;
    float* y1 = (float*)(wsb + off); off += (size_t)BSROWS * EE * 4;

    // 1. weight transpose + bf16 convert
    transpose_bf16<<<dim3(DD/32, EE/32, HH), 256, 0, stream>>>(Wq, WqT, EE, DD);
    transpose_bf16<<<dim3(DD/32, EE/32, HH), 256, 0, stream>>>(Wv, WvT, EE, DD);
    transpose_bf16<<<dim3(EE/32, HD/32, 1),  256, 0, stream>>>(Wo, WoT, HD, EE);
    transpose_bf16<<<dim3(FF/32, EE/32, 1),  256, 0, stream>>>(W1, W1T, EE, FF);
    transpose_bf16<<<dim3(FF/32, FF/32, 1),  256, 0, stream>>>(W2, W2T, FF, FF);
    transpose_bf16<<<dim3(EE/32, FF/32, 1),  256, 0, stream>>>(W3, W3T, FF, EE);
    // 2. LN1 -> bf16
    ln_kernel<bf16><<<BSROWS, 256, 0, stream>>>(x, ln1g, ln1b, xln);
    // 3. q/v projections (f32 out for attention)
    dim3 gp(HD / 128, BSROWS / 128);
    mfma_gemm<float, false, false><<<gp, 256, 0, stream>>>(xln, WqT, bq, nullptr, qb, BSROWS, HD, EE);
    mfma_gemm<float, false, false><<<gp, 256, 0, stream>>>(xln, WvT, bv, nullptr, vb, BSROWS, HD, EE);
    // 4. attention (f32 in, bf16 out)
    attn_kernel<<<dim3(SS / 64, HH, BB), 256, 0, stream>>>(qb, vb, mask, attno);
    // 5. O-proj + residual x -> y1 (f32, ws)
    mfma_gemm<float, false, true><<<gp, 256, 0, stream>>>(attno, WoT, bo, x, y1, BSROWS, EE, HD);
    // 6. LN2: y1 -> y1ln (bf16, reuse xln)
    bf16* y1ln = xln;
    ln_kernel<bf16><<<BSROWS, 256, 0, stream>>>(y1, ln2g, ln2b, y1ln);
    // 7. FF1: h1 = relu(y1ln @ W1 + b1), bf16
    dim3 gf(FF / 128, BSROWS / 128);
    mfma_gemm<bf16, true, false><<<gf, 256, 0, stream>>>(y1ln, W1T, b1, nullptr, h1, BSROWS, FF, EE);
    // 8. FF2: h2 = relu(h1 @ W2 + b2), bf16
    mfma_gemm<bf16, true, false><<<gf, 256, 0, stream>>>(h1, W2T, b2, nullptr, h2, BSROWS, FF, FF);
    // 9. FF3: out = h2 @ W3 + b3 + y1   (d_out written once, never read)
    mfma_gemm<float, false, true><<<gp, 256, 0, stream>>>(h2, W3T, b3, y1, out, BSROWS, EE, FF);
}

// Round 4
// 356.682 us; speedup vs baseline: 7.6387x; 3.6425x over previous
//
#include <hip/hip_runtime.h>
#include <hip/hip_bf16.h>
#include <math.h>

// Problem constants
#define BB 2
#define SS 2048
#define EE 768
#define HH 12
#define DD 64
#define FF 3072
#define BSROWS (BB*SS)      // 4096
#define HD (HH*DD)          // 768

typedef __hip_bfloat16 bf16;
typedef __attribute__((ext_vector_type(8))) short short8;
typedef __attribute__((ext_vector_type(4))) float f32x4;

__device__ inline void store_val(float* p, float v) { *p = v; }
__device__ inline void store_val(bf16* p, float v)  { *p = __float2bfloat16(v); }

// ---------------------------------------------------------------------------
// Tiled transpose + f32->bf16 convert: in [R,C] f32 (z-slice) -> out [C,R] bf16
// ---------------------------------------------------------------------------
__global__ __launch_bounds__(256)
void transpose_bf16(const float* __restrict__ in, bf16* __restrict__ out,
                    int R, int C)
{
    __shared__ float tile[32][33];
    const int t = threadIdx.x;
    const size_t zoff = (size_t)blockIdx.z * R * C;
    const int r0 = blockIdx.y * 32, c0 = blockIdx.x * 32;
    const int lr = t >> 5, lc = t & 31;
    #pragma unroll
    for (int i = 0; i < 4; ++i)
        tile[lr + 8 * i][lc] = in[zoff + (size_t)(r0 + lr + 8 * i) * C + c0 + lc];
    __syncthreads();
    #pragma unroll
    for (int i = 0; i < 4; ++i)
        out[zoff + (size_t)(c0 + lr + 8 * i) * R + r0 + lc] =
            __float2bfloat16(tile[lc][lr + 8 * i]);
}

// ---------------------------------------------------------------------------
// V transpose: vbf [B*S, HD] (head-h 64-col slice) -> vt [B*H, 64, S] bf16
// ---------------------------------------------------------------------------
__global__ __launch_bounds__(256)
void transpose_v(const bf16* __restrict__ in, bf16* __restrict__ out)
{
    __shared__ bf16 tile[64][72];
    const int bh = blockIdx.y;
    const int b = bh / HH, h = bh - b * HH;
    const int s0 = blockIdx.x * 64;
    const int t = threadIdx.x;
    const int r = t >> 2, cg = (t & 3) * 16;
    const bf16* src = in + ((size_t)(b * SS + s0 + r) * HD + h * 64 + cg);
    #pragma unroll
    for (int i = 0; i < 2; ++i)
        *(short8*)&tile[r][cg + i * 8] = *(const short8*)(src + i * 8);
    __syncthreads();
    bf16* dst = out + (((size_t)bh * 64 + r) * SS + s0 + cg);
    #pragma unroll
    for (int i = 0; i < 2; ++i) {
        short8 v;
        #pragma unroll
        for (int j = 0; j < 8; ++j)
            v[j] = *(const short*)&tile[cg + i * 8 + j][r];
        *(short8*)(dst + i * 8) = v;
    }
}

// ---------------------------------------------------------------------------
// LayerNorm: one block (256 thr) per row of 768; f32 in, OutT out
// ---------------------------------------------------------------------------
template<typename OutT>
__global__ __launch_bounds__(256)
void ln_kernel(const float* __restrict__ x, const float* __restrict__ g,
               const float* __restrict__ bt, OutT* __restrict__ o)
{
    const int row = blockIdx.x;
    const float* xr = x + (size_t)row * EE;
    const int t = threadIdx.x;
    float v0 = xr[t], v1 = xr[t + 256], v2 = xr[t + 512];
    float s = v0 + v1 + v2;
    #pragma unroll
    for (int off = 32; off > 0; off >>= 1) s += __shfl_xor(s, off);
    __shared__ float red[8];
    const int w = t >> 6;
    if ((t & 63) == 0) red[w] = s;
    __syncthreads();
    const float mean = (red[0] + red[1] + red[2] + red[3]) * (1.f / 768.f);
    float d0 = v0 - mean, d1 = v1 - mean, d2 = v2 - mean;
    float q = d0 * d0 + d1 * d1 + d2 * d2;
    #pragma unroll
    for (int off = 32; off > 0; off >>= 1) q += __shfl_xor(q, off);
    if ((t & 63) == 0) red[4 + w] = q;
    __syncthreads();
    const float var = (red[4] + red[5] + red[6] + red[7]) * (1.f / 768.f);
    const float rstd = rsqrtf(var + 1e-5f);
    OutT* orow = o + (size_t)row * EE;
    store_val(&orow[t],       d0 * rstd * g[t]       + bt[t]);
    store_val(&orow[t + 256], d1 * rstd * g[t + 256] + bt[t + 256]);
    store_val(&orow[t + 512], d2 * rstd * g[t + 512] + bt[t + 512]);
}

// ---------------------------------------------------------------------------
// bf16 MFMA GEMM: C[M,N] = A[M,K](bf16) @ Bt[N,K](bf16)^T + bias (+res)(relu?)
// 128x128 tile, BK=64, 4 waves (2x2), wave tile 64x64 (4x4 frags of 16x16x32).
// LDS chunk slot = c ^ (row&7): XOR swizzle applied on the pre-swizzled GLOBAL
// source (LDS dest linear); read applies the same XOR. res/C must not alias.
// ---------------------------------------------------------------------------
template<typename OutT, bool RELU, bool HAS_RES>
__global__ __launch_bounds__(256, 2)
void mfma_gemm(const bf16* __restrict__ A, const bf16* __restrict__ Bt,
               const float* __restrict__ bias, const float* __restrict__ res,
               OutT* __restrict__ C, int M, int N, int K)
{
    __shared__ bf16 As[128 * 64];
    __shared__ bf16 Bs[128 * 64];
    const int t = threadIdx.x;
    const int lane = t & 63;
    const int w = t >> 6;
    const int wm = w >> 1, wn = w & 1;
    const int m0 = blockIdx.y * 128, n0 = blockIdx.x * 128;
    const int fr = lane & 15;
    const int fq = lane >> 4;

    f32x4 acc[4][4];
    #pragma unroll
    for (int i = 0; i < 4; ++i)
        #pragma unroll
        for (int j = 0; j < 4; ++j)
            acc[i][j] = (f32x4){0.f, 0.f, 0.f, 0.f};

    for (int k0 = 0; k0 < K; k0 += 64) {
        asm volatile("s_waitcnt lgkmcnt(0)" ::: "memory");
        __syncthreads();
        #pragma unroll
        for (int i = 0; i < 4; ++i) {
            const int p = (w * 4 + i) * 64 + lane;
            const int m = p >> 3;
            const int c = (p & 7) ^ (m & 7);
            const bf16* ga = &A [(size_t)(m0 + m) * K + k0 + c * 8];
            const bf16* gb = &Bt[(size_t)(n0 + m) * K + k0 + c * 8];
            bf16* la = &As[(size_t)(w * 4 + i) * 512];
            bf16* lb = &Bs[(size_t)(w * 4 + i) * 512];
            __builtin_amdgcn_global_load_lds(
                (const __attribute__((address_space(1))) unsigned int*)ga,
                (__attribute__((address_space(3))) unsigned int*)la, 16, 0, 0);
            __builtin_amdgcn_global_load_lds(
                (const __attribute__((address_space(1))) unsigned int*)gb,
                (__attribute__((address_space(3))) unsigned int*)lb, 16, 0, 0);
        }
        asm volatile("s_waitcnt vmcnt(0)" ::: "memory");
        __syncthreads();

        short8 af[4][2], bfr[4][2];
        #pragma unroll
        for (int mi = 0; mi < 4; ++mi) {
            const int row = wm * 64 + mi * 16 + fr;
            #pragma unroll
            for (int kh = 0; kh < 2; ++kh) {
                const int slot = (kh * 4 + fq) ^ (row & 7);
                af[mi][kh] = *(const short8*)&As[row * 64 + slot * 8];
            }
        }
        #pragma unroll
        for (int ni = 0; ni < 4; ++ni) {
            const int row = wn * 64 + ni * 16 + fr;
            #pragma unroll
            for (int kh = 0; kh < 2; ++kh) {
                const int slot = (kh * 4 + fq) ^ (row & 7);
                bfr[ni][kh] = *(const short8*)&Bs[row * 64 + slot * 8];
            }
        }
        #pragma unroll
        for (int mi = 0; mi < 4; ++mi)
            #pragma unroll
            for (int ni = 0; ni < 4; ++ni) {
                acc[mi][ni] = __builtin_amdgcn_mfma_f32_16x16x32_bf16(
                    af[mi][0], bfr[ni][0], acc[mi][ni], 0, 0, 0);
                acc[mi][ni] = __builtin_amdgcn_mfma_f32_16x16x32_bf16(
                    af[mi][1], bfr[ni][1], acc[mi][ni], 0, 0, 0);
            }
    }

    #pragma unroll
    for (int ni = 0; ni < 4; ++ni) {
        const int cn = n0 + wn * 64 + ni * 16 + fr;
        const float bv = bias[cn];
        #pragma unroll
        for (int mi = 0; mi < 4; ++mi) {
            const int rbase = m0 + wm * 64 + mi * 16 + fq * 4;
            #pragma unroll
            for (int j = 0; j < 4; ++j) {
                float v = acc[mi][ni][j] + bv;
                if (HAS_RES) v += res[(size_t)(rbase + j) * N + cn];
                if (RELU) v = fmaxf(v, 0.f);
                store_val(&C[(size_t)(rbase + j) * N + cn], v);
            }
        }
    }
}

// ---------------------------------------------------------------------------
// MFMA flash attention. q layout [B*S, HD] bf16 (k = q, source bug);
// vt [B*H, 64(d), S] bf16. Causal + input_mask cols; all-masked row ->
// diagonal p=1 injected at final tile (=> out = v[row], matches reference).
// Block: 256 thr = 4 waves, 64 q-rows (16/wave), kv-tiles of 64.
// Frag layouts (verified): A/B lane l -> row l&15, k (l>>4)*8+j;
//                          C/D lane l -> col l&15, row (l>>4)*4+reg.
// ---------------------------------------------------------------------------
__global__ __launch_bounds__(256, 2)
void attn_mfma(const bf16* __restrict__ qg, const bf16* __restrict__ vtg,
               const int* __restrict__ maskg, bf16* __restrict__ outg)
{
    const int qt = blockIdx.x;   // 0..31
    const int h  = blockIdx.y;
    const int b  = blockIdx.z;
    __shared__ bf16 Ks[64 * 64];   // XOR-swizzled K rows (= q rows)
    __shared__ bf16 Vts[64 * 64];  // XOR-swizzled Vt rows [d][kv]
    __shared__ bf16 Ps[64][72];    // P row-major [q][kv], pad 8 (144B stride)
    __shared__ int  msk[64];
    const int t = threadIdx.x;
    const int lane = t & 63;
    const int w = t >> 6;
    const int fr = lane & 15;
    const int g  = lane >> 4;
    const int q0 = qt * 64;

    // ---- stage own Q tile into Ks, extract A-frags to registers ----
    #pragma unroll
    for (int i = 0; i < 2; ++i) {
        const int pc = i * 256 + t;
        const int m = pc >> 3, c = (pc & 7) ^ (m & 7);
        const bf16* src = qg + ((size_t)(b * SS + q0 + m) * HD + h * 64 + c * 8);
        __builtin_amdgcn_global_load_lds(
            (const __attribute__((address_space(1))) unsigned int*)src,
            (__attribute__((address_space(3))) unsigned int*)&Ks[pc * 8], 16, 0, 0);
    }
    asm volatile("s_waitcnt vmcnt(0)" ::: "memory");
    __syncthreads();
    short8 qa[2];
    {
        const int row = w * 16 + fr;
        #pragma unroll
        for (int s = 0; s < 2; ++s) {
            const int slot = (s * 4 + g) ^ (row & 7);
            qa[s] = *(const short8*)&Ks[row * 64 + slot * 8];
        }
    }

    f32x4 o_acc[4];
    #pragma unroll
    for (int i = 0; i < 4; ++i) o_acc[i] = (f32x4){0.f, 0.f, 0.f, 0.f};
    float run_m[4], run_l[4];
    #pragma unroll
    for (int j = 0; j < 4; ++j) { run_m[j] = -INFINITY; run_l[j] = 0.f; }

    for (int kvt = 0; kvt <= qt; ++kvt) {
        const int kv0 = kvt * 64;
        asm volatile("s_waitcnt lgkmcnt(0)" ::: "memory");
        __syncthreads();   // all waves done reading Ks/Vts (and qa pre-loop)
        #pragma unroll
        for (int i = 0; i < 2; ++i) {
            const int pc = i * 256 + t;
            const int m = pc >> 3, c = (pc & 7) ^ (m & 7);
            const bf16* ksrc = qg  + ((size_t)(b * SS + kv0 + m) * HD + h * 64 + c * 8);
            const bf16* vsrc = vtg + (((size_t)(b * HH + h) * 64 + m) * SS + kv0 + c * 8);
            __builtin_amdgcn_global_load_lds(
                (const __attribute__((address_space(1))) unsigned int*)ksrc,
                (__attribute__((address_space(3))) unsigned int*)&Ks[pc * 8], 16, 0, 0);
            __builtin_amdgcn_global_load_lds(
                (const __attribute__((address_space(1))) unsigned int*)vsrc,
                (__attribute__((address_space(3))) unsigned int*)&Vts[pc * 8], 16, 0, 0);
        }
        if (t < 64) msk[t] = maskg[b * SS + kv0 + t];
        asm volatile("s_waitcnt vmcnt(0)" ::: "memory");
        __syncthreads();

        // ---- QK^T: S[q, kv] ----
        f32x4 acc_s[4];
        #pragma unroll
        for (int ni = 0; ni < 4; ++ni) acc_s[ni] = (f32x4){0.f, 0.f, 0.f, 0.f};
        #pragma unroll
        for (int ni = 0; ni < 4; ++ni) {
            const int row = ni * 16 + fr;
            #pragma unroll
            for (int s = 0; s < 2; ++s) {
                const int slot = (s * 4 + g) ^ (row & 7);
                short8 kb = *(const short8*)&Ks[row * 64 + slot * 8];
                acc_s[ni] = __builtin_amdgcn_mfma_f32_16x16x32_bf16(
                    qa[s], kb, acc_s[ni], 0, 0, 0);
            }
        }

        // ---- masked online softmax (rows = g*4+j, cols = ni*16+fr) ----
        int mv[4];
        #pragma unroll
        for (int ni = 0; ni < 4; ++ni) mv[ni] = msk[ni * 16 + fr];
        float sv[4][4], mj[4], alpha[4];
        #pragma unroll
        for (int j = 0; j < 4; ++j) mj[j] = -INFINITY;
        #pragma unroll
        for (int ni = 0; ni < 4; ++ni) {
            const int kvcol = kv0 + ni * 16 + fr;
            const bool mok = (mv[ni] != 0);
            #pragma unroll
            for (int j = 0; j < 4; ++j) {
                const int qrow = q0 + w * 16 + g * 4 + j;
                const bool valid = mok && (kvcol <= qrow);
                const float s = valid ? acc_s[ni][j] * 0.125f : -INFINITY;
                sv[ni][j] = s;
                mj[j] = fmaxf(mj[j], s);
            }
        }
        #pragma unroll
        for (int j = 0; j < 4; ++j) {
            #pragma unroll
            for (int off = 1; off < 16; off <<= 1)
                mj[j] = fmaxf(mj[j], __shfl_xor(mj[j], off));
            const float newm = fmaxf(run_m[j], mj[j]);
            const float al = (newm == -INFINITY) ? 1.f : __expf(run_m[j] - newm);
            float ts = 0.f;
            #pragma unroll
            for (int ni = 0; ni < 4; ++ni) {
                float pv = (sv[ni][j] == -INFINITY) ? 0.f : __expf(sv[ni][j] - newm);
                if (kvt == qt && newm == -INFINITY) {
                    const int dloc = w * 16 + g * 4 + j;   // diag: kv==qrow
                    if ((dloc >> 4) == ni && (dloc & 15) == fr) pv = 1.f;
                }
                sv[ni][j] = pv;
                ts += pv;
            }
            #pragma unroll
            for (int off = 1; off < 16; off <<= 1) ts += __shfl_xor(ts, off);
            run_l[j] = run_l[j] * al + ts;
            run_m[j] = newm;
            alpha[j] = al;
        }
        // write P (bf16) to LDS; rescale o
        #pragma unroll
        for (int ni = 0; ni < 4; ++ni)
            #pragma unroll
            for (int j = 0; j < 4; ++j)
                Ps[w * 16 + g * 4 + j][ni * 16 + fr] = __float2bfloat16(sv[ni][j]);
        #pragma unroll
        for (int nt = 0; nt < 4; ++nt)
            #pragma unroll
            for (int j = 0; j < 4; ++j)
                o_acc[nt][j] *= alpha[j];

        // ---- PV: o[q, d] += P[q, kv] @ Vt[d, kv]^T ----
        short8 pa[2];
        #pragma unroll
        for (int s = 0; s < 2; ++s)
            pa[s] = *(const short8*)&Ps[w * 16 + fr][s * 32 + g * 8];
        #pragma unroll
        for (int nt = 0; nt < 4; ++nt) {
            const int row = nt * 16 + fr;
            #pragma unroll
            for (int s = 0; s < 2; ++s) {
                const int slot = (s * 4 + g) ^ (row & 7);
                short8 vb = *(const short8*)&Vts[row * 64 + slot * 8];
                o_acc[nt] = __builtin_amdgcn_mfma_f32_16x16x32_bf16(
                    pa[s], vb, o_acc[nt], 0, 0, 0);
            }
        }
    }

    // ---- epilogue ----
    float inv[4];
    #pragma unroll
    for (int j = 0; j < 4; ++j) inv[j] = (run_l[j] > 0.f) ? 1.f / run_l[j] : 0.f;
    #pragma unroll
    for (int nt = 0; nt < 4; ++nt)
        #pragma unroll
        for (int j = 0; j < 4; ++j)
            outg[(size_t)(b * SS + q0 + w * 16 + g * 4 + j) * HD + h * 64 + nt * 16 + fr]
                = __float2bfloat16(o_acc[nt][j] * inv[j]);
}

// ---------------------------------------------------------------------------
extern "C" void kernel_launch(void* const* d_in, const int* in_sizes, int n_in,
                              void* d_out, int out_size, void* d_ws, size_t ws_size,
                              hipStream_t stream)
{
    const float* x    = (const float*)d_in[0];
    const float* Wq   = (const float*)d_in[1];
    const float* bq   = (const float*)d_in[2];
    const float* Wv   = (const float*)d_in[3];
    const float* bv   = (const float*)d_in[4];
    const float* Wo   = (const float*)d_in[5];
    const float* bo   = (const float*)d_in[6];
    const float* ln1g = (const float*)d_in[7];
    const float* ln1b = (const float*)d_in[8];
    const float* W1   = (const float*)d_in[9];
    const float* b1   = (const float*)d_in[10];
    const float* W2   = (const float*)d_in[11];
    const float* b2   = (const float*)d_in[12];
    const float* W3   = (const float*)d_in[13];
    const float* b3   = (const float*)d_in[14];
    const float* ln2g = (const float*)d_in[15];
    const float* ln2b = (const float*)d_in[16];
    const int*   mask = (const int*)d_in[17];
    float* out = (float*)d_out;
    char* wsb  = (char*)d_ws;

    // workspace (~96.4 MB). Liveness aliasing: h1 (25.2MB) overlays
    // [qbf|vbf|vt|attno] (all dead by FF1); xln reused as y1ln.
    size_t off = 0;
    bf16* WqT = (bf16*)(wsb + off); off += (size_t)EE * HD * 2;
    bf16* WvT = (bf16*)(wsb + off); off += (size_t)EE * HD * 2;
    bf16* WoT = (bf16*)(wsb + off); off += (size_t)HD * EE * 2;
    bf16* W1T = (bf16*)(wsb + off); off += (size_t)EE * FF * 2;
    bf16* W3T = (bf16*)(wsb + off); off += (size_t)FF * EE * 2;
    bf16* W2T = (bf16*)(wsb + off); off += (size_t)FF * FF * 2;
    bf16* qbf = (bf16*)(wsb + off);
    bf16* h1  = qbf;                 off += (size_t)BSROWS * HD * 2;
    bf16* vbf = (bf16*)(wsb + off);  off += (size_t)BSROWS * HD * 2;
    bf16* vt  = (bf16*)(wsb + off);  off += (size_t)BSROWS * HD * 2;
    bf16* attno = (bf16*)(wsb + off); off += (size_t)BSROWS * HD * 2;
    bf16* xln = (bf16*)(wsb + off);  off += (size_t)BSROWS * EE * 2;
    bf16* h2  = (bf16*)(wsb + off);  off += (size_t)BSROWS * FF * 2;
    float* y1 = (float*)(wsb + off); off += (size_t)BSROWS * EE * 4;

    // 1. weight transpose + bf16 convert
    transpose_bf16<<<dim3(DD/32, EE/32, HH), 256, 0, stream>>>(Wq, WqT, EE, DD);
    transpose_bf16<<<dim3(DD/32, EE/32, HH), 256, 0, stream>>>(Wv, WvT, EE, DD);
    transpose_bf16<<<dim3(EE/32, HD/32, 1),  256, 0, stream>>>(Wo, WoT, HD, EE);
    transpose_bf16<<<dim3(FF/32, EE/32, 1),  256, 0, stream>>>(W1, W1T, EE, FF);
    transpose_bf16<<<dim3(FF/32, FF/32, 1),  256, 0, stream>>>(W2, W2T, FF, FF);
    transpose_bf16<<<dim3(EE/32, FF/32, 1),  256, 0, stream>>>(W3, W3T, FF, EE);
    // 2. LN1 -> bf16
    ln_kernel<bf16><<<BSROWS, 256, 0, stream>>>(x, ln1g, ln1b, xln);
    // 3. q/v projections -> bf16
    dim3 gp(HD / 128, BSROWS / 128);
    mfma_gemm<bf16, false, false><<<gp, 256, 0, stream>>>(xln, WqT, bq, nullptr, qbf, BSROWS, HD, EE);
    mfma_gemm<bf16, false, false><<<gp, 256, 0, stream>>>(xln, WvT, bv, nullptr, vbf, BSROWS, HD, EE);
    // 4. V transpose -> vt [B*H, 64, S]
    transpose_v<<<dim3(SS/64, BB*HH), 256, 0, stream>>>(vbf, vt);
    // 5. MFMA flash attention -> attno (bf16)
    attn_mfma<<<dim3(SS/64, HH, BB), 256, 0, stream>>>(qbf, vt, mask, attno);
    // 6. O-proj + residual x -> y1 (f32)
    mfma_gemm<float, false, true><<<gp, 256, 0, stream>>>(attno, WoT, bo, x, y1, BSROWS, EE, HD);
    // 7. LN2: y1 -> y1ln (reuse xln)
    bf16* y1ln = xln;
    ln_kernel<bf16><<<BSROWS, 256, 0, stream>>>(y1, ln2g, ln2b, y1ln);
    // 8. FF1: h1 = relu(y1ln @ W1 + b1)
    dim3 gf(FF / 128, BSROWS / 128);
    mfma_gemm<bf16, true, false><<<gf, 256, 0, stream>>>(y1ln, W1T, b1, nullptr, h1, BSROWS, FF, EE);
    // 9. FF2: h2 = relu(h1 @ W2 + b2)
    mfma_gemm<bf16, true, false><<<gf, 256, 0, stream>>>(h1, W2T, b2, nullptr, h2, BSROWS, FF, FF);
    // 10. FF3: out = h2 @ W3 + b3 + y1
    mfma_gemm<float, false, true><<<gp, 256, 0, stream>>>(h2, W3T, b3, y1, out, BSROWS, EE, FF);
}

// Round 6
// 352.491 us; speedup vs baseline: 7.7295x; 1.0119x over previous
//
#include <hip/hip_runtime.h>
#include <hip/hip_bf16.h>
#include <math.h>

// Problem constants
#define BB 2
#define SS 2048
#define EE 768
#define HH 12
#define DD 64
#define FF 3072
#define BSROWS (BB*SS)      // 4096
#define HD (HH*DD)          // 768

typedef __hip_bfloat16 bf16;
typedef __attribute__((ext_vector_type(8))) short short8;
typedef __attribute__((ext_vector_type(4))) float f32x4;

__device__ inline void store_val(float* p, float v) { *p = v; }
__device__ inline void store_val(bf16* p, float v)  { *p = __float2bfloat16(v); }

// ---------------------------------------------------------------------------
// Tiled transpose + f32->bf16 convert: in [R,C] f32 (z-slice) -> out [C,R] bf16
// ---------------------------------------------------------------------------
__global__ __launch_bounds__(256)
void transpose_bf16(const float* __restrict__ in, bf16* __restrict__ out,
                    int R, int C)
{
    __shared__ float tile[32][33];
    const int t = threadIdx.x;
    const size_t zoff = (size_t)blockIdx.z * R * C;
    const int r0 = blockIdx.y * 32, c0 = blockIdx.x * 32;
    const int lr = t >> 5, lc = t & 31;
    #pragma unroll
    for (int i = 0; i < 4; ++i)
        tile[lr + 8 * i][lc] = in[zoff + (size_t)(r0 + lr + 8 * i) * C + c0 + lc];
    __syncthreads();
    #pragma unroll
    for (int i = 0; i < 4; ++i)
        out[zoff + (size_t)(c0 + lr + 8 * i) * R + r0 + lc] =
            __float2bfloat16(tile[lc][lr + 8 * i]);
}

// ---------------------------------------------------------------------------
// LayerNorm: one block (256 thr) per row of 768; f32 in, OutT out
// ---------------------------------------------------------------------------
template<typename OutT>
__global__ __launch_bounds__(256)
void ln_kernel(const float* __restrict__ x, const float* __restrict__ g,
               const float* __restrict__ bt, OutT* __restrict__ o)
{
    const int row = blockIdx.x;
    const float* xr = x + (size_t)row * EE;
    const int t = threadIdx.x;
    float v0 = xr[t], v1 = xr[t + 256], v2 = xr[t + 512];
    float s = v0 + v1 + v2;
    #pragma unroll
    for (int off = 32; off > 0; off >>= 1) s += __shfl_xor(s, off);
    __shared__ float red[8];
    const int w = t >> 6;
    if ((t & 63) == 0) red[w] = s;
    __syncthreads();
    const float mean = (red[0] + red[1] + red[2] + red[3]) * (1.f / 768.f);
    float d0 = v0 - mean, d1 = v1 - mean, d2 = v2 - mean;
    float q = d0 * d0 + d1 * d1 + d2 * d2;
    #pragma unroll
    for (int off = 32; off > 0; off >>= 1) q += __shfl_xor(q, off);
    if ((t & 63) == 0) red[4 + w] = q;
    __syncthreads();
    const float var = (red[4] + red[5] + red[6] + red[7]) * (1.f / 768.f);
    const float rstd = rsqrtf(var + 1e-5f);
    OutT* orow = o + (size_t)row * EE;
    store_val(&orow[t],       d0 * rstd * g[t]       + bt[t]);
    store_val(&orow[t + 256], d1 * rstd * g[t + 256] + bt[t + 256]);
    store_val(&orow[t + 512], d2 * rstd * g[t + 512] + bt[t + 512]);
}

// ---------------------------------------------------------------------------
// bf16 MFMA GEMM: C[M,N] = A[M,K](bf16) @ Bt[N,K](bf16)^T + bias (+res)(relu?)
// 128x128 tile, BK=64, 4 waves (2x2), wave tile 64x64 (4x4 frags of 16x16x32).
// LDS chunk slot = c ^ (row&7): XOR swizzle applied on the pre-swizzled GLOBAL
// source (LDS dest linear); read applies the same XOR. res/C must not alias.
// VT: write C transposed per-head as vt[B*H, 64(d), S] (for attention V^T).
// ---------------------------------------------------------------------------
template<typename OutT, bool RELU, bool HAS_RES, bool VT = false>
__global__ __launch_bounds__(256, 2)
void mfma_gemm(const bf16* __restrict__ A, const bf16* __restrict__ Bt,
               const float* __restrict__ bias, const float* __restrict__ res,
               OutT* __restrict__ C, int M, int N, int K)
{
    __shared__ bf16 As[128 * 64];
    __shared__ bf16 Bs[128 * 64];
    const int t = threadIdx.x;
    const int lane = t & 63;
    const int w = t >> 6;
    const int wm = w >> 1, wn = w & 1;
    const int m0 = blockIdx.y * 128, n0 = blockIdx.x * 128;
    const int fr = lane & 15;
    const int fq = lane >> 4;

    f32x4 acc[4][4];
    #pragma unroll
    for (int i = 0; i < 4; ++i)
        #pragma unroll
        for (int j = 0; j < 4; ++j)
            acc[i][j] = (f32x4){0.f, 0.f, 0.f, 0.f};

    for (int k0 = 0; k0 < K; k0 += 64) {
        asm volatile("s_waitcnt lgkmcnt(0)" ::: "memory");
        __syncthreads();
        #pragma unroll
        for (int i = 0; i < 4; ++i) {
            const int p = (w * 4 + i) * 64 + lane;
            const int m = p >> 3;
            const int c = (p & 7) ^ (m & 7);
            const bf16* ga = &A [(size_t)(m0 + m) * K + k0 + c * 8];
            const bf16* gb = &Bt[(size_t)(n0 + m) * K + k0 + c * 8];
            bf16* la = &As[(size_t)(w * 4 + i) * 512];
            bf16* lb = &Bs[(size_t)(w * 4 + i) * 512];
            __builtin_amdgcn_global_load_lds(
                (const __attribute__((address_space(1))) unsigned int*)ga,
                (__attribute__((address_space(3))) unsigned int*)la, 16, 0, 0);
            __builtin_amdgcn_global_load_lds(
                (const __attribute__((address_space(1))) unsigned int*)gb,
                (__attribute__((address_space(3))) unsigned int*)lb, 16, 0, 0);
        }
        asm volatile("s_waitcnt vmcnt(0)" ::: "memory");
        __syncthreads();

        short8 af[4][2], bfr[4][2];
        #pragma unroll
        for (int mi = 0; mi < 4; ++mi) {
            const int row = wm * 64 + mi * 16 + fr;
            #pragma unroll
            for (int kh = 0; kh < 2; ++kh) {
                const int slot = (kh * 4 + fq) ^ (row & 7);
                af[mi][kh] = *(const short8*)&As[row * 64 + slot * 8];
            }
        }
        #pragma unroll
        for (int ni = 0; ni < 4; ++ni) {
            const int row = wn * 64 + ni * 16 + fr;
            #pragma unroll
            for (int kh = 0; kh < 2; ++kh) {
                const int slot = (kh * 4 + fq) ^ (row & 7);
                bfr[ni][kh] = *(const short8*)&Bs[row * 64 + slot * 8];
            }
        }
        #pragma unroll
        for (int mi = 0; mi < 4; ++mi)
            #pragma unroll
            for (int ni = 0; ni < 4; ++ni) {
                acc[mi][ni] = __builtin_amdgcn_mfma_f32_16x16x32_bf16(
                    af[mi][0], bfr[ni][0], acc[mi][ni], 0, 0, 0);
                acc[mi][ni] = __builtin_amdgcn_mfma_f32_16x16x32_bf16(
                    af[mi][1], bfr[ni][1], acc[mi][ni], 0, 0, 0);
            }
    }

    // epilogue: C/D layout col=lane&15, row=(lane>>4)*4+reg  [m89/m91]
    #pragma unroll
    for (int ni = 0; ni < 4; ++ni) {
        const int cn = n0 + wn * 64 + ni * 16 + fr;
        const float bv = bias[cn];
        #pragma unroll
        for (int mi = 0; mi < 4; ++mi) {
            const int rbase = m0 + wm * 64 + mi * 16 + fq * 4;
            if (VT) {
                // vt[((b*HH + h)*64 + d)*SS + s]; 4 consecutive s -> 8B store
                const int bidx = rbase >> 11, sidx = rbase & (SS - 1);
                const int hh = cn >> 6, dd = cn & 63;
                alignas(8) bf16 tmp[4];
                #pragma unroll
                for (int j = 0; j < 4; ++j)
                    tmp[j] = __float2bfloat16(acc[mi][ni][j] + bv);
                *(ushort4*)((bf16*)C + (((size_t)(bidx * HH + hh) * 64 + dd) * SS + sidx))
                    = *(const ushort4*)tmp;
            } else {
                #pragma unroll
                for (int j = 0; j < 4; ++j) {
                    float v = acc[mi][ni][j] + bv;
                    if (HAS_RES) v += res[(size_t)(rbase + j) * N + cn];
                    if (RELU) v = fmaxf(v, 0.f);
                    store_val(&C[(size_t)(rbase + j) * N + cn], v);
                }
            }
        }
    }
}

// ---------------------------------------------------------------------------
// MFMA flash attention (round-4 structure: single-buffered, Q via LDS).
// q layout [B*S, HD] bf16 (k = q, source bug); vt [B*H, 64(d), S] bf16.
// Causal + input_mask cols; all-masked row -> diagonal p=1 at final tile
// (=> out = v[row], matches reference).
// Sched-only tweaks vs round 4: reversed qt block order, setprio around MFMA.
// ---------------------------------------------------------------------------
__global__ __launch_bounds__(256, 2)
void attn_mfma(const bf16* __restrict__ qg, const bf16* __restrict__ vtg,
               const int* __restrict__ maskg, bf16* __restrict__ outg)
{
    const int qt = (int)(gridDim.x - 1 - blockIdx.x);   // 31..0 (big tiles first)
    const int h  = blockIdx.y;
    const int b  = blockIdx.z;
    __shared__ bf16 Ks[64 * 64];   // XOR-swizzled K rows (= q rows)
    __shared__ bf16 Vts[64 * 64];  // XOR-swizzled Vt rows [d][kv]
    __shared__ bf16 Ps[64][72];    // P row-major [q][kv] (wave-local rows)
    __shared__ int  msk[64];
    const int t = threadIdx.x;
    const int lane = t & 63;
    const int w = t >> 6;
    const int fr = lane & 15;
    const int g  = lane >> 4;
    const int q0 = qt * 64;

    // ---- stage own Q tile into Ks, extract A-frags to registers ----
    #pragma unroll
    for (int i = 0; i < 2; ++i) {
        const int pc = i * 256 + t;
        const int m = pc >> 3, c = (pc & 7) ^ (m & 7);
        const bf16* src = qg + ((size_t)(b * SS + q0 + m) * HD + h * 64 + c * 8);
        __builtin_amdgcn_global_load_lds(
            (const __attribute__((address_space(1))) unsigned int*)src,
            (__attribute__((address_space(3))) unsigned int*)&Ks[pc * 8], 16, 0, 0);
    }
    asm volatile("s_waitcnt vmcnt(0)" ::: "memory");
    __syncthreads();
    short8 qa[2];
    {
        const int row = w * 16 + fr;
        #pragma unroll
        for (int s = 0; s < 2; ++s) {
            const int slot = (s * 4 + g) ^ (row & 7);
            qa[s] = *(const short8*)&Ks[row * 64 + slot * 8];
        }
    }

    f32x4 o_acc[4];
    #pragma unroll
    for (int i = 0; i < 4; ++i) o_acc[i] = (f32x4){0.f, 0.f, 0.f, 0.f};
    float run_m[4], run_l[4];
    #pragma unroll
    for (int j = 0; j < 4; ++j) { run_m[j] = -INFINITY; run_l[j] = 0.f; }

    for (int kvt = 0; kvt <= qt; ++kvt) {
        const int kv0 = kvt * 64;
        asm volatile("s_waitcnt lgkmcnt(0)" ::: "memory");
        __syncthreads();   // all waves done reading Ks/Vts (and qa pre-loop)
        #pragma unroll
        for (int i = 0; i < 2; ++i) {
            const int pc = i * 256 + t;
            const int m = pc >> 3, c = (pc & 7) ^ (m & 7);
            const bf16* ksrc = qg  + ((size_t)(b * SS + kv0 + m) * HD + h * 64 + c * 8);
            const bf16* vsrc = vtg + (((size_t)(b * HH + h) * 64 + m) * SS + kv0 + c * 8);
            __builtin_amdgcn_global_load_lds(
                (const __attribute__((address_space(1))) unsigned int*)ksrc,
                (__attribute__((address_space(3))) unsigned int*)&Ks[pc * 8], 16, 0, 0);
            __builtin_amdgcn_global_load_lds(
                (const __attribute__((address_space(1))) unsigned int*)vsrc,
                (__attribute__((address_space(3))) unsigned int*)&Vts[pc * 8], 16, 0, 0);
        }
        if (t < 64) msk[t] = maskg[b * SS + kv0 + t];
        asm volatile("s_waitcnt vmcnt(0)" ::: "memory");
        __syncthreads();

        // ---- QK^T: S[q, kv] ----
        f32x4 acc_s[4];
        #pragma unroll
        for (int ni = 0; ni < 4; ++ni) acc_s[ni] = (f32x4){0.f, 0.f, 0.f, 0.f};
        __builtin_amdgcn_s_setprio(1);
        #pragma unroll
        for (int ni = 0; ni < 4; ++ni) {
            const int row = ni * 16 + fr;
            #pragma unroll
            for (int s = 0; s < 2; ++s) {
                const int slot = (s * 4 + g) ^ (row & 7);
                short8 kb = *(const short8*)&Ks[row * 64 + slot * 8];
                acc_s[ni] = __builtin_amdgcn_mfma_f32_16x16x32_bf16(
                    qa[s], kb, acc_s[ni], 0, 0, 0);
            }
        }
        __builtin_amdgcn_s_setprio(0);

        // ---- masked online softmax (rows = g*4+j, cols = ni*16+fr) ----
        int mv[4];
        #pragma unroll
        for (int ni = 0; ni < 4; ++ni) mv[ni] = msk[ni * 16 + fr];
        float sv[4][4], mj[4], alpha[4];
        #pragma unroll
        for (int j = 0; j < 4; ++j) mj[j] = -INFINITY;
        #pragma unroll
        for (int ni = 0; ni < 4; ++ni) {
            const int kvcol = kv0 + ni * 16 + fr;
            const bool mok = (mv[ni] != 0);
            #pragma unroll
            for (int j = 0; j < 4; ++j) {
                const int qrow = q0 + w * 16 + g * 4 + j;
                const bool valid = mok && (kvcol <= qrow);
                const float s = valid ? acc_s[ni][j] * 0.125f : -INFINITY;
                sv[ni][j] = s;
                mj[j] = fmaxf(mj[j], s);
            }
        }
        #pragma unroll
        for (int j = 0; j < 4; ++j) {
            #pragma unroll
            for (int off = 1; off < 16; off <<= 1)
                mj[j] = fmaxf(mj[j], __shfl_xor(mj[j], off));
            const float newm = fmaxf(run_m[j], mj[j]);
            const float al = (newm == -INFINITY) ? 1.f : __expf(run_m[j] - newm);
            float ts = 0.f;
            #pragma unroll
            for (int ni = 0; ni < 4; ++ni) {
                float pv = (sv[ni][j] == -INFINITY) ? 0.f : __expf(sv[ni][j] - newm);
                if (kvt == qt && newm == -INFINITY) {
                    const int dloc = w * 16 + g * 4 + j;   // diag: kv==qrow
                    if ((dloc >> 4) == ni && (dloc & 15) == fr) pv = 1.f;
                }
                sv[ni][j] = pv;
                ts += pv;
            }
            #pragma unroll
            for (int off = 1; off < 16; off <<= 1) ts += __shfl_xor(ts, off);
            run_l[j] = run_l[j] * al + ts;
            run_m[j] = newm;
            alpha[j] = al;
        }
        // write P (bf16) to wave-local LDS rows; rescale o
        #pragma unroll
        for (int ni = 0; ni < 4; ++ni)
            #pragma unroll
            for (int j = 0; j < 4; ++j)
                Ps[w * 16 + g * 4 + j][ni * 16 + fr] = __float2bfloat16(sv[ni][j]);
        #pragma unroll
        for (int nt = 0; nt < 4; ++nt)
            #pragma unroll
            for (int j = 0; j < 4; ++j)
                o_acc[nt][j] *= alpha[j];

        // ---- PV: o[q, d] += P[q, kv] @ Vt[d, kv]^T ----
        short8 pa[2];
        #pragma unroll
        for (int s = 0; s < 2; ++s)
            pa[s] = *(const short8*)&Ps[w * 16 + fr][s * 32 + g * 8];
        __builtin_amdgcn_s_setprio(1);
        #pragma unroll
        for (int nt = 0; nt < 4; ++nt) {
            const int row = nt * 16 + fr;
            #pragma unroll
            for (int s = 0; s < 2; ++s) {
                const int slot = (s * 4 + g) ^ (row & 7);
                short8 vb = *(const short8*)&Vts[row * 64 + slot * 8];
                o_acc[nt] = __builtin_amdgcn_mfma_f32_16x16x32_bf16(
                    pa[s], vb, o_acc[nt], 0, 0, 0);
            }
        }
        __builtin_amdgcn_s_setprio(0);
    }

    // ---- epilogue ----
    float inv[4];
    #pragma unroll
    for (int j = 0; j < 4; ++j) inv[j] = (run_l[j] > 0.f) ? 1.f / run_l[j] : 0.f;
    #pragma unroll
    for (int nt = 0; nt < 4; ++nt)
        #pragma unroll
        for (int j = 0; j < 4; ++j)
            outg[(size_t)(b * SS + q0 + w * 16 + g * 4 + j) * HD + h * 64 + nt * 16 + fr]
                = __float2bfloat16(o_acc[nt][j] * inv[j]);
}

// ---------------------------------------------------------------------------
extern "C" void kernel_launch(void* const* d_in, const int* in_sizes, int n_in,
                              void* d_out, int out_size, void* d_ws, size_t ws_size,
                              hipStream_t stream)
{
    const float* x    = (const float*)d_in[0];
    const float* Wq   = (const float*)d_in[1];
    const float* bq   = (const float*)d_in[2];
    const float* Wv   = (const float*)d_in[3];
    const float* bv   = (const float*)d_in[4];
    const float* Wo   = (const float*)d_in[5];
    const float* bo   = (const float*)d_in[6];
    const float* ln1g = (const float*)d_in[7];
    const float* ln1b = (const float*)d_in[8];
    const float* W1   = (const float*)d_in[9];
    const float* b1   = (const float*)d_in[10];
    const float* W2   = (const float*)d_in[11];
    const float* b2   = (const float*)d_in[12];
    const float* W3   = (const float*)d_in[13];
    const float* b3   = (const float*)d_in[14];
    const float* ln2g = (const float*)d_in[15];
    const float* ln2b = (const float*)d_in[16];
    const int*   mask = (const int*)d_in[17];
    float* out = (float*)d_out;
    char* wsb  = (char*)d_ws;

    // workspace (~96.4 MB). Liveness aliasing: h1 (25.2MB) overlays
    // [qbf|vt|attno|pad] (all dead by FF1); xln reused as y1ln.
    size_t off = 0;
    bf16* WqT = (bf16*)(wsb + off); off += (size_t)EE * HD * 2;
    bf16* WvT = (bf16*)(wsb + off); off += (size_t)EE * HD * 2;
    bf16* WoT = (bf16*)(wsb + off); off += (size_t)HD * EE * 2;
    bf16* W1T = (bf16*)(wsb + off); off += (size_t)EE * FF * 2;
    bf16* W3T = (bf16*)(wsb + off); off += (size_t)FF * EE * 2;
    bf16* W2T = (bf16*)(wsb + off); off += (size_t)FF * FF * 2;
    bf16* qbf = (bf16*)(wsb + off);
    bf16* h1  = qbf;                  off += (size_t)BSROWS * HD * 2;
    bf16* vt  = (bf16*)(wsb + off);   off += (size_t)BSROWS * HD * 2;
    bf16* attno = (bf16*)(wsb + off); off += (size_t)BSROWS * HD * 2;
    /* pad for h1 tail */             off += (size_t)BSROWS * HD * 2;
    bf16* xln = (bf16*)(wsb + off);   off += (size_t)BSROWS * EE * 2;
    bf16* h2  = (bf16*)(wsb + off);   off += (size_t)BSROWS * FF * 2;
    float* y1 = (float*)(wsb + off);  off += (size_t)BSROWS * EE * 4;

    // 1. weight transpose + bf16 convert
    transpose_bf16<<<dim3(DD/32, EE/32, HH), 256, 0, stream>>>(Wq, WqT, EE, DD);
    transpose_bf16<<<dim3(DD/32, EE/32, HH), 256, 0, stream>>>(Wv, WvT, EE, DD);
    transpose_bf16<<<dim3(EE/32, HD/32, 1),  256, 0, stream>>>(Wo, WoT, HD, EE);
    transpose_bf16<<<dim3(FF/32, EE/32, 1),  256, 0, stream>>>(W1, W1T, EE, FF);
    transpose_bf16<<<dim3(FF/32, FF/32, 1),  256, 0, stream>>>(W2, W2T, FF, FF);
    transpose_bf16<<<dim3(EE/32, FF/32, 1),  256, 0, stream>>>(W3, W3T, FF, EE);
    // 2. LN1 -> bf16
    ln_kernel<bf16><<<BSROWS, 256, 0, stream>>>(x, ln1g, ln1b, xln);
    // 3. q projection -> qbf; v projection -> vt [B*H, 64, S] (fused transpose)
    dim3 gp(HD / 128, BSROWS / 128);
    mfma_gemm<bf16, false, false><<<gp, 256, 0, stream>>>(xln, WqT, bq, nullptr, qbf, BSROWS, HD, EE);
    mfma_gemm<bf16, false, false, true><<<gp, 256, 0, stream>>>(xln, WvT, bv, nullptr, vt, BSROWS, HD, EE);
    // 4. MFMA flash attention -> attno (bf16)
    attn_mfma<<<dim3(SS/64, HH, BB), 256, 0, stream>>>(qbf, vt, mask, attno);
    // 5. O-proj + residual x -> y1 (f32)
    mfma_gemm<float, false, true><<<gp, 256, 0, stream>>>(attno, WoT, bo, x, y1, BSROWS, EE, HD);
    // 6. LN2: y1 -> y1ln (reuse xln)
    bf16* y1ln = xln;
    ln_kernel<bf16><<<BSROWS, 256, 0, stream>>>(y1, ln2g, ln2b, y1ln);
    // 7. FF1: h1 = relu(y1ln @ W1 + b1)
    dim3 gf(FF / 128, BSROWS / 128);
    mfma_gemm<bf16, true, false><<<gf, 256, 0, stream>>>(y1ln, W1T, b1, nullptr, h1, BSROWS, FF, EE);
    // 8. FF2: h2 = relu(h1 @ W2 + b2)
    mfma_gemm<bf16, true, false><<<gf, 256, 0, stream>>>(h1, W2T, b2, nullptr, h2, BSROWS, FF, FF);
    // 9. FF3: out = h2 @ W3 + b3 + y1
    mfma_gemm<float, false, true><<<gp, 256, 0, stream>>>(h2, W3T, b3, y1, out, BSROWS, EE, FF);
}